// Round 7
// baseline (294.039 us; speedup 1.0000x reference)
//
#include <hip/hip_runtime.h>
#include <stdint.h>
#include <stddef.h>

// DecoderMHA: x[4,2048,1024] fp32 -> out fp32 [4,2048,1024]
// cvt(fused) -> QKV gemm (V transposed via LDS epilogue) ->
// block-cooperative LDS-staged flash attn (16 rows/wave, 16 waves/CU) -> out proj.

typedef __bf16 bf16;
typedef __bf16 bf16x8 __attribute__((ext_vector_type(8)));
typedef __bf16 bf16x4 __attribute__((ext_vector_type(4)));
typedef float f32x4 __attribute__((ext_vector_type(4)));

#define DM   1024
#define NH   16
#define DK   64
#define BSZ  4
#define SEQL 2048
#define NTOK 8192   // BSZ*SEQL
#define NEGB -3.0e38f

__device__ __forceinline__ void async16(const bf16* g, bf16* l) {
  __builtin_amdgcn_global_load_lds(
      (__attribute__((address_space(1))) void*)g,
      (__attribute__((address_space(3))) void*)l, 16, 0, 0);
}

// ---------------- fused converts: x->bf16, W*4->bf16, pad->float bias ----------
__global__ __launch_bounds__(256) void cvt_all(
    const float* __restrict__ x,
    const float* __restrict__ w0, const float* __restrict__ w1,
    const float* __restrict__ w2, const float* __restrict__ w3,
    const int* __restrict__ pad,
    bf16* __restrict__ xd,
    bf16* __restrict__ d0, bf16* __restrict__ d1,
    bf16* __restrict__ d2, bf16* __restrict__ d3,
    float* __restrict__ padf) {
  int blk = blockIdx.x;
  if (blk >= 6144) {  // pad bias: 4 blocks x 2048 entries
    int i = (blk - 6144) * 2048 + threadIdx.x * 8;
    int4 p0 = *(const int4*)(pad + i);
    int4 p1 = *(const int4*)(pad + i + 4);
    float4 o0 = {p0.x ? NEGB : 0.f, p0.y ? NEGB : 0.f, p0.z ? NEGB : 0.f, p0.w ? NEGB : 0.f};
    float4 o1 = {p1.x ? NEGB : 0.f, p1.y ? NEGB : 0.f, p1.z ? NEGB : 0.f, p1.w ? NEGB : 0.f};
    *(float4*)(padf + i) = o0;
    *(float4*)(padf + i + 4) = o1;
    return;
  }
  const float* s; bf16* d; int i;
  if (blk < 4096) { s = x; d = xd; i = blk * 2048 + threadIdx.x * 8; }
  else {
    int m = (blk - 4096) >> 9, bi = (blk - 4096) & 511;
    switch (m) {
      case 0:  s = w0; d = d0; break;
      case 1:  s = w1; d = d1; break;
      case 2:  s = w2; d = d2; break;
      default: s = w3; d = d3; break;
    }
    i = bi * 2048 + threadIdx.x * 8;
  }
  float4 v0 = *(const float4*)(s + i);
  float4 v1 = *(const float4*)(s + i + 4);
  bf16x8 o = {(bf16)v0.x, (bf16)v0.y, (bf16)v0.z, (bf16)v0.w,
              (bf16)v1.x, (bf16)v1.y, (bf16)v1.z, (bf16)v1.w};
  *(bf16x8*)(d + i) = o;
}

// ---------------- 128x128 bf16 GEMM body (C = A @ W^T + bias) ----------------
// OUT_MODE 0: bf16 out head-split [B,H,S,dk]; 1: fp32 flat [M,1024];
// OUT_MODE 2: bf16 out TRANSPOSED head-split [B,H,dk,S] via per-wave LDS transpose
template <int OUT_MODE>
__device__ __forceinline__ void gemm128(const bf16* __restrict__ A,
                                        const bf16* __restrict__ W,
                                        const float* __restrict__ bias,
                                        void* __restrict__ outp) {
  __shared__ bf16 As[128 * 32];
  __shared__ bf16 Bs[128 * 32];
  const int tid  = threadIdx.x;
  const int lane = tid & 63;
  const int wv   = tid >> 6;
  const int wm   = (wv & 1) * 64;
  const int wn   = (wv >> 1) * 64;
  const int c    = lane & 15;
  const int quad = lane >> 4;
  const int bm   = blockIdx.y * 128;
  const int bn   = blockIdx.x * 128;

  f32x4 acc[4][4] = {};

  for (int k0 = 0; k0 < DM; k0 += 32) {
    __syncthreads();
#pragma unroll
    for (int j = 0; j < 2; ++j) {
      int i = j * 256 + tid;
      async16(A + (size_t)(bm + (i >> 2)) * DM + k0 + (i & 3) * 8, As + i * 8);
      async16(W + (size_t)(bn + (i >> 2)) * DM + k0 + (i & 3) * 8, Bs + i * 8);
    }
    __syncthreads();
    bf16x8 af[4], bg[4];
#pragma unroll
    for (int mi = 0; mi < 4; ++mi)
      af[mi] = *(const bf16x8*)&As[(wm + mi * 16 + c) * 32 + quad * 8];
#pragma unroll
    for (int ni = 0; ni < 4; ++ni)
      bg[ni] = *(const bf16x8*)&Bs[(wn + ni * 16 + c) * 32 + quad * 8];
#pragma unroll
    for (int mi = 0; mi < 4; ++mi)
#pragma unroll
      for (int ni = 0; ni < 4; ++ni)
        acc[mi][ni] = __builtin_amdgcn_mfma_f32_16x16x32_bf16(af[mi], bg[ni],
                                                              acc[mi][ni], 0, 0, 0);
  }

  float bias_r[4];
#pragma unroll
  for (int ni = 0; ni < 4; ++ni) bias_r[ni] = bias[bn + wn + ni * 16 + c];

  if constexpr (OUT_MODE == 2) {
    // per-wave 64x64 transpose in LDS (wave-private -> no barrier), then
    // coalesced b128 stores: each Vt d-row is 128 B contiguous in s.
    __shared__ bf16 Vtr[4][64 * 72];
    bf16* vt = &Vtr[wv][0];
#pragma unroll
    for (int mi = 0; mi < 4; ++mi)
#pragma unroll
      for (int ni = 0; ni < 4; ++ni) {
        bf16x4 pv = {(bf16)(acc[mi][ni][0] + bias_r[ni]),
                     (bf16)(acc[mi][ni][1] + bias_r[ni]),
                     (bf16)(acc[mi][ni][2] + bias_r[ni]),
                     (bf16)(acc[mi][ni][3] + bias_r[ni])};
        *(bf16x4*)&vt[(ni * 16 + c) * 72 + mi * 16 + quad * 4] = pv;
      }
    const int base = bm + wm;                 // s base (one b: 2048 % 128 == 0)
    const int bb = base >> 11, s0 = base & 2047;
    const int rl = lane >> 3, cl = lane & 7;
#pragma unroll
    for (int it = 0; it < 8; ++it) {
      int d_row = it * 8 + rl;
      bf16x8 v = *(const bf16x8*)&vt[d_row * 72 + cl * 8];
      int n_g = bn + wn + d_row;
      int hh = n_g >> 6, dd = n_g & 63;
      *(bf16x8*)&((bf16*)outp)[(((size_t)(bb * NH + hh)) * DK + dd) * SEQL + s0 + cl * 8] = v;
    }
    return;
  }

#pragma unroll
  for (int mi = 0; mi < 4; ++mi) {
#pragma unroll
    for (int reg = 0; reg < 4; ++reg) {
      int m_g = bm + wm + mi * 16 + quad * 4 + reg;
#pragma unroll
      for (int ni = 0; ni < 4; ++ni) {
        int n_g = bn + wn + ni * 16 + c;
        float v = acc[mi][ni][reg] + bias_r[ni];
        if (OUT_MODE == 0) {
          int b = m_g >> 11, s = m_g & 2047;
          int h = n_g >> 6, d = n_g & 63;
          ((bf16*)outp)[(((size_t)(b * NH + h) * SEQL + s) << 6) + d] = (bf16)v;
        } else {
          ((float*)outp)[(size_t)m_g * DM + n_g] = v;
        }
      }
    }
  }
}

__global__ __launch_bounds__(256) void qkv_gemm(
    const bf16* __restrict__ X,
    const bf16* __restrict__ Wq, const bf16* __restrict__ Wk, const bf16* __restrict__ Wv,
    const float* __restrict__ bq, const float* __restrict__ bk, const float* __restrict__ bv,
    bf16* __restrict__ Q, bf16* __restrict__ K, bf16* __restrict__ Vt) {
  if (blockIdx.z == 0)      gemm128<0>(X, Wq, bq, Q);
  else if (blockIdx.z == 1) gemm128<0>(X, Wk, bk, K);
  else                      gemm128<2>(X, Wv, bv, Vt);
}

__global__ __launch_bounds__(256) void out_gemm(const bf16* __restrict__ A,
                                                const bf16* __restrict__ W,
                                                const float* __restrict__ bias,
                                                float* __restrict__ out) {
  gemm128<1>(A, W, bias, out);
}

// ---------------- block-cooperative LDS-staged flash attention ----------------
// Block = 4 waves sharing a 64-row q-tile; wave wv owns rows wv*16..wv*16+15.
// K/V staged once per block per 32-key tile via global_load_lds (double-buffered,
// 1 barrier/tile). Block work item = causal pair of 64-row tiles (u, 31-u):
// all 1024 blocks do exactly 68 key-tiles -> zero drain; 4 blocks/CU = 16 waves/CU.
// XCD swizzle: 8 bh per XCD.
#define PSTR 40

__global__ __launch_bounds__(256) void attn_kernel(
    const bf16* __restrict__ Q, const bf16* __restrict__ K,
    const bf16* __restrict__ Vt, const float* __restrict__ padf,
    bf16* __restrict__ O) {
  const int B = blockIdx.x;            // 1024
  const int xcd = B & 7;
  const int g = B >> 3;                // 0..127
  const int bh = xcd + 8 * (g >> 4);   // 8 bh per XCD
  const int t = g & 15;                // pair index 0..15
  const int b = bh >> 4, h = bh & 15;
  const int tid  = threadIdx.x;
  const int lane = tid & 63;
  const int wv   = tid >> 6;
  const int c    = lane & 15;
  const int quad = lane >> 4;

  __shared__ bf16 KsS[2][32 * 64];     // XOR-swizzled 16B chunks
  __shared__ bf16 VsS[2][64 * 32];     // linear [d][s_local]
  __shared__ bf16 Plds_all[4][16 * PSTR];
  bf16* Plds = &Plds_all[wv][0];

  const bf16* Qh  = Q  + (size_t)bh * SEQL * DK;
  const bf16* Kh  = K  + (size_t)bh * SEQL * DK;
  const bf16* Vth = Vt + (size_t)bh * DK * SEQL;
  const float* pb = padf + b * SEQL;

  // staging lane constants
  const int kr = lane >> 3;            // K: row within wave's 8-row slice
  const int kj = (lane & 7) ^ kr;      // K: 16B chunk (XOR swizzle)
  const int vr = lane >> 2;            // V: row within wave's 16-row slice
  const int vj = lane & 3;             // V: 16B chunk within 64B row

  const float sc = 0.1803368801111204f;  // log2(e) / sqrt(64)

  for (int pass = 0; pass < 2; ++pass) {
    const int qt  = pass ? 31 - t : t;     // 64-row q-tile index
    const int R   = qt * 64 + wv * 16;     // wave's first q row
    const int nkt = qt * 2 + 2;

    // Q fragments (B-operand): lane c = query, k = kh*32 + quad*8 + j
    bf16x8 Qf[2];
#pragma unroll
    for (int kh = 0; kh < 2; ++kh)
      Qf[kh] = *(const bf16x8*)&Qh[(size_t)(R + c) * DK + kh * 32 + quad * 8];

    f32x4 Oc[4] = {};
    float l_s = 0.f;

    __syncthreads();  // previous pass done reading buffers
    // stage tile 0 into buf 0
    async16(Kh + (size_t)(wv * 8 + kr) * DK + kj * 8, &KsS[0][(wv * 64 + lane) * 8]);
    async16(Vth + (size_t)(wv * 16 + vr) * SEQL + vj * 8, &VsS[0][(wv * 64 + lane) * 8]);

    for (int kt = 0; kt < nkt; ++kt) {
      const int cur = kt & 1, nxt = cur ^ 1;
      const int kb = kt * 32;
      __syncthreads();  // drains asyncs: buf[cur] ready; buf[nxt] free

      if (kt + 1 < nkt) {
        const int kb2 = kb + 32;
        async16(Kh + (size_t)(kb2 + wv * 8 + kr) * DK + kj * 8,
                &KsS[nxt][(wv * 64 + lane) * 8]);
        async16(Vth + (size_t)(wv * 16 + vr) * SEQL + kb2 + vj * 8,
                &VsS[nxt][(wv * 64 + lane) * 8]);
      }
      if (kb > R + 15) continue;  // fully masked for this wave

      float4 bc[2];
#pragma unroll
      for (int kf = 0; kf < 2; ++kf)
        bc[kf] = *(const float4*)&pb[kb + kf * 16 + quad * 4];

      // LDS -> fragments
      bf16x8 Kf[2][2], Vf[4];
#pragma unroll
      for (int kf = 0; kf < 2; ++kf) {
        const int rloc = kf * 16 + c;
#pragma unroll
        for (int kh = 0; kh < 2; ++kh) {
          const int j = kh * 4 + quad;
          Kf[kf][kh] = *(const bf16x8*)&KsS[cur][(rloc * 8 + (j ^ (rloc & 7))) * 8];
        }
      }
#pragma unroll
      for (int df = 0; df < 4; ++df)
        Vf[df] = *(const bf16x8*)&VsS[cur][(df * 16 + c) * 32 + quad * 8];

      // S^T = K.Q^T  (col=query, row=key)
      f32x4 st[2] = {};
#pragma unroll
      for (int kh = 0; kh < 2; ++kh)
#pragma unroll
        for (int kf = 0; kf < 2; ++kf)
          st[kf] = __builtin_amdgcn_mfma_f32_16x16x32_bf16(Kf[kf][kh], Qf[kh],
                                                           st[kf], 0, 0, 0);

      // softmax (no max-subtraction) + P store; masked keys -> exp2(-3e38)=0
      const bool diag = (kb + 31 > R);
      float p8[8];
#pragma unroll
      for (int kf = 0; kf < 2; ++kf) {
        const float* bv4 = (const float*)&bc[kf];
#pragma unroll
        for (int r = 0; r < 4; ++r) {
          float e = __builtin_amdgcn_exp2f(__builtin_fmaf(st[kf][r], sc, bv4[r]));
          if (diag && (kb + kf * 16 + quad * 4 + r > R + c)) e = 0.f;
          p8[kf * 4 + r] = e;
          l_s += e;
        }
      }
      bf16x4 pk0 = {(bf16)p8[0], (bf16)p8[1], (bf16)p8[2], (bf16)p8[3]};
      bf16x4 pk1 = {(bf16)p8[4], (bf16)p8[5], (bf16)p8[6], (bf16)p8[7]};
      *(bf16x4*)&Plds[c * PSTR + quad * 4] = pk0;
      *(bf16x4*)&Plds[c * PSTR + 16 + quad * 4] = pk1;

      // O += P @ V
      bf16x8 af = *(const bf16x8*)&Plds[c * PSTR + quad * 8];
#pragma unroll
      for (int df = 0; df < 4; ++df)
        Oc[df] = __builtin_amdgcn_mfma_f32_16x16x32_bf16(af, Vf[df], Oc[df], 0, 0, 0);
    }

    // epilogue: reduce l across quads, divide, store
    float l = l_s;
    l += __shfl_xor(l, 16);
    l += __shfl_xor(l, 32);
    float linv = (l > 0.f) ? 1.f / l : 0.f;
    float lr[4];
#pragma unroll
    for (int r = 0; r < 4; ++r) lr[r] = __shfl(linv, quad * 4 + r);
#pragma unroll
    for (int r = 0; r < 4; ++r) {
      size_t row = (size_t)(b * SEQL + R + quad * 4 + r) * DM + h * DK;
#pragma unroll
      for (int df = 0; df < 4; ++df)
        O[row + df * 16 + c] = (bf16)(Oc[df][r] * lr[r]);
    }
  }
}

// ---------------- launch ----------------
extern "C" void kernel_launch(void* const* d_in, const int* in_sizes, int n_in,
                              void* d_out, int out_size, void* d_ws, size_t ws_size,
                              hipStream_t stream) {
  const float* x   = (const float*)d_in[0];
  const int*   pad = (const int*)d_in[1];
  const float* Wq  = (const float*)d_in[2];
  const float* bq  = (const float*)d_in[3];
  const float* Wk  = (const float*)d_in[4];
  const float* bk  = (const float*)d_in[5];
  const float* Wv  = (const float*)d_in[6];
  const float* bv  = (const float*)d_in[7];
  const float* Wo  = (const float*)d_in[8];
  const float* bo  = (const float*)d_in[9];
  float* out = (float*)d_out;

  const size_t SZ_X = (size_t)NTOK * DM * 2;  // 16 MB
  const size_t SZ_W = (size_t)DM * DM * 2;    // 2 MB
  char* ws = (char*)d_ws;
  bf16* Xb  = (bf16*)ws;  ws += SZ_X;
  bf16* Wqb = (bf16*)ws;  ws += SZ_W;
  bf16* Wkb = (bf16*)ws;  ws += SZ_W;
  bf16* Wvb = (bf16*)ws;  ws += SZ_W;
  bf16* Wob = (bf16*)ws;  ws += SZ_W;
  bf16* Qb  = (bf16*)ws;  ws += SZ_X;
  bf16* Kb  = (bf16*)ws;  ws += SZ_X;
  bf16* Vtb = (bf16*)ws;  ws += SZ_X;   // [B,H,dk,S]
  bf16* Ob  = (bf16*)ws;  ws += SZ_X;
  float* padfb = (float*)ws; ws += (size_t)NTOK * 4;

  cvt_all<<<6148, 256, 0, stream>>>(x, Wq, Wk, Wv, Wo, pad,
                                    Xb, Wqb, Wkb, Wvb, Wob, padfb);
  qkv_gemm<<<dim3(8, 64, 3), 256, 0, stream>>>(Xb, Wqb, Wkb, Wvb, bq, bk, bv, Qb, Kb, Vtb);
  attn_kernel<<<1024, 256, 0, stream>>>(Qb, Kb, Vtb, padfb, Ob);
  out_gemm<<<dim3(8, 64), 256, 0, stream>>>(Ob, Wob, bo, out);
}

// Round 8
// 273.533 us; speedup vs baseline: 1.0750x; 1.0750x over previous
//
#include <hip/hip_runtime.h>
#include <stdint.h>
#include <stddef.h>

// DecoderMHA: x[4,2048,1024] fp32 -> out fp32 [4,2048,1024]
// cvt(fused) -> QKV gemm (V transposed via LDS epilogue) ->
// flash attn: 512-thr blocks, 8 waves x 16 q-rows share one 128-row q-tile -> out proj.

typedef __bf16 bf16;
typedef __bf16 bf16x8 __attribute__((ext_vector_type(8)));
typedef __bf16 bf16x4 __attribute__((ext_vector_type(4)));
typedef float f32x4 __attribute__((ext_vector_type(4)));

#define DM   1024
#define NH   16
#define DK   64
#define BSZ  4
#define SEQL 2048
#define NTOK 8192   // BSZ*SEQL
#define NEGB -3.0e38f

__device__ __forceinline__ void async16(const bf16* g, bf16* l) {
  __builtin_amdgcn_global_load_lds(
      (__attribute__((address_space(1))) void*)g,
      (__attribute__((address_space(3))) void*)l, 16, 0, 0);
}

// ---------------- fused converts: x->bf16, W*4->bf16, pad->float bias ----------
__global__ __launch_bounds__(256) void cvt_all(
    const float* __restrict__ x,
    const float* __restrict__ w0, const float* __restrict__ w1,
    const float* __restrict__ w2, const float* __restrict__ w3,
    const int* __restrict__ pad,
    bf16* __restrict__ xd,
    bf16* __restrict__ d0, bf16* __restrict__ d1,
    bf16* __restrict__ d2, bf16* __restrict__ d3,
    float* __restrict__ padf) {
  int blk = blockIdx.x;
  if (blk >= 6144) {  // pad bias: 4 blocks x 2048 entries
    int i = (blk - 6144) * 2048 + threadIdx.x * 8;
    int4 p0 = *(const int4*)(pad + i);
    int4 p1 = *(const int4*)(pad + i + 4);
    float4 o0 = {p0.x ? NEGB : 0.f, p0.y ? NEGB : 0.f, p0.z ? NEGB : 0.f, p0.w ? NEGB : 0.f};
    float4 o1 = {p1.x ? NEGB : 0.f, p1.y ? NEGB : 0.f, p1.z ? NEGB : 0.f, p1.w ? NEGB : 0.f};
    *(float4*)(padf + i) = o0;
    *(float4*)(padf + i + 4) = o1;
    return;
  }
  const float* s; bf16* d; int i;
  if (blk < 4096) { s = x; d = xd; i = blk * 2048 + threadIdx.x * 8; }
  else {
    int m = (blk - 4096) >> 9, bi = (blk - 4096) & 511;
    switch (m) {
      case 0:  s = w0; d = d0; break;
      case 1:  s = w1; d = d1; break;
      case 2:  s = w2; d = d2; break;
      default: s = w3; d = d3; break;
    }
    i = bi * 2048 + threadIdx.x * 8;
  }
  float4 v0 = *(const float4*)(s + i);
  float4 v1 = *(const float4*)(s + i + 4);
  bf16x8 o = {(bf16)v0.x, (bf16)v0.y, (bf16)v0.z, (bf16)v0.w,
              (bf16)v1.x, (bf16)v1.y, (bf16)v1.z, (bf16)v1.w};
  *(bf16x8*)(d + i) = o;
}

// ---------------- 128x128 bf16 GEMM body (C = A @ W^T + bias) ----------------
// OUT_MODE 0: bf16 out head-split [B,H,S,dk]; 1: fp32 flat [M,1024];
// OUT_MODE 2: bf16 out TRANSPOSED head-split [B,H,dk,S] via per-wave LDS transpose
template <int OUT_MODE>
__device__ __forceinline__ void gemm128(const bf16* __restrict__ A,
                                        const bf16* __restrict__ W,
                                        const float* __restrict__ bias,
                                        void* __restrict__ outp) {
  __shared__ bf16 As[128 * 32];
  __shared__ bf16 Bs[128 * 32];
  const int tid  = threadIdx.x;
  const int lane = tid & 63;
  const int wv   = tid >> 6;
  const int wm   = (wv & 1) * 64;
  const int wn   = (wv >> 1) * 64;
  const int c    = lane & 15;
  const int quad = lane >> 4;
  const int bm   = blockIdx.y * 128;
  const int bn   = blockIdx.x * 128;

  f32x4 acc[4][4] = {};

  for (int k0 = 0; k0 < DM; k0 += 32) {
    __syncthreads();
#pragma unroll
    for (int j = 0; j < 2; ++j) {
      int i = j * 256 + tid;
      async16(A + (size_t)(bm + (i >> 2)) * DM + k0 + (i & 3) * 8, As + i * 8);
      async16(W + (size_t)(bn + (i >> 2)) * DM + k0 + (i & 3) * 8, Bs + i * 8);
    }
    __syncthreads();
    bf16x8 af[4], bg[4];
#pragma unroll
    for (int mi = 0; mi < 4; ++mi)
      af[mi] = *(const bf16x8*)&As[(wm + mi * 16 + c) * 32 + quad * 8];
#pragma unroll
    for (int ni = 0; ni < 4; ++ni)
      bg[ni] = *(const bf16x8*)&Bs[(wn + ni * 16 + c) * 32 + quad * 8];
#pragma unroll
    for (int mi = 0; mi < 4; ++mi)
#pragma unroll
      for (int ni = 0; ni < 4; ++ni)
        acc[mi][ni] = __builtin_amdgcn_mfma_f32_16x16x32_bf16(af[mi], bg[ni],
                                                              acc[mi][ni], 0, 0, 0);
  }

  float bias_r[4];
#pragma unroll
  for (int ni = 0; ni < 4; ++ni) bias_r[ni] = bias[bn + wn + ni * 16 + c];

  if constexpr (OUT_MODE == 2) {
    // per-wave 64x64 transpose in LDS (wave-private -> no barrier), then
    // coalesced b128 stores: each Vt d-row is 128 B contiguous in s.
    __shared__ bf16 Vtr[4][64 * 72];
    bf16* vt = &Vtr[wv][0];
#pragma unroll
    for (int mi = 0; mi < 4; ++mi)
#pragma unroll
      for (int ni = 0; ni < 4; ++ni) {
        bf16x4 pv = {(bf16)(acc[mi][ni][0] + bias_r[ni]),
                     (bf16)(acc[mi][ni][1] + bias_r[ni]),
                     (bf16)(acc[mi][ni][2] + bias_r[ni]),
                     (bf16)(acc[mi][ni][3] + bias_r[ni])};
        *(bf16x4*)&vt[(ni * 16 + c) * 72 + mi * 16 + quad * 4] = pv;
      }
    const int base = bm + wm;                 // s base (one b: 2048 % 128 == 0)
    const int bb = base >> 11, s0 = base & 2047;
    const int rl = lane >> 3, cl = lane & 7;
#pragma unroll
    for (int it = 0; it < 8; ++it) {
      int d_row = it * 8 + rl;
      bf16x8 v = *(const bf16x8*)&vt[d_row * 72 + cl * 8];
      int n_g = bn + wn + d_row;
      int hh = n_g >> 6, dd = n_g & 63;
      *(bf16x8*)&((bf16*)outp)[(((size_t)(bb * NH + hh)) * DK + dd) * SEQL + s0 + cl * 8] = v;
    }
    return;
  }

#pragma unroll
  for (int mi = 0; mi < 4; ++mi) {
#pragma unroll
    for (int reg = 0; reg < 4; ++reg) {
      int m_g = bm + wm + mi * 16 + quad * 4 + reg;
#pragma unroll
      for (int ni = 0; ni < 4; ++ni) {
        int n_g = bn + wn + ni * 16 + c;
        float v = acc[mi][ni][reg] + bias_r[ni];
        if (OUT_MODE == 0) {
          int b = m_g >> 11, s = m_g & 2047;
          int h = n_g >> 6, d = n_g & 63;
          ((bf16*)outp)[(((size_t)(b * NH + h) * SEQL + s) << 6) + d] = (bf16)v;
        } else {
          ((float*)outp)[(size_t)m_g * DM + n_g] = v;
        }
      }
    }
  }
}

__global__ __launch_bounds__(256) void qkv_gemm(
    const bf16* __restrict__ X,
    const bf16* __restrict__ Wq, const bf16* __restrict__ Wk, const bf16* __restrict__ Wv,
    const float* __restrict__ bq, const float* __restrict__ bk, const float* __restrict__ bv,
    bf16* __restrict__ Q, bf16* __restrict__ K, bf16* __restrict__ Vt) {
  if (blockIdx.z == 0)      gemm128<0>(X, Wq, bq, Q);
  else if (blockIdx.z == 1) gemm128<0>(X, Wk, bk, K);
  else                      gemm128<2>(X, Wv, bv, Vt);
}

__global__ __launch_bounds__(256) void out_gemm(const bf16* __restrict__ A,
                                                const bf16* __restrict__ W,
                                                const float* __restrict__ bias,
                                                float* __restrict__ out) {
  gemm128<1>(A, W, bias, out);
}

// ---------------- flash attention: 8 waves x 16 rows, 128-row q-tile ----------------
// Block = 512 threads = 8 waves sharing a 128-row q-tile (wave wv: rows wv*16..+15).
// K/V staged once per block per 32-key tile (waves 0-3 stage K, 4-7 stage V),
// double-buffered, 1 barrier/tile. Work item = causal pair (t, 15-t): all 512
// blocks do exactly 68 key-tiles; 2 blocks/CU = 16 waves/CU. XCD swizzle: 8 bh/XCD.
// K LDS: 3-bit XOR chunk swizzle; V LDS: 2-bit XOR chunk swizzle (8 lanes/bank-group
// on every b128 read = structural optimum; write side folded into source address).
#define PSTR 40

__global__ __launch_bounds__(512) void attn_kernel(
    const bf16* __restrict__ Q, const bf16* __restrict__ K,
    const bf16* __restrict__ Vt, const float* __restrict__ padf,
    bf16* __restrict__ O) {
  const int B = blockIdx.x;            // 512
  const int xcd = B & 7;
  const int g = B >> 3;                // 0..63
  const int bh = xcd + 8 * (g >> 3);   // 8 bh per XCD
  const int t = g & 7;                 // pair index 0..7
  const int b = bh >> 4, h = bh & 15;
  const int tid  = threadIdx.x;
  const int lane = tid & 63;
  const int wv   = tid >> 6;           // 0..7
  const int c    = lane & 15;
  const int quad = lane >> 4;

  __shared__ bf16 KsS[2][32 * 64];     // 32 keys x 128B, 3-bit XOR chunk swizzle
  __shared__ bf16 VsS[2][64 * 32];     // 64 d x 64B, 2-bit XOR chunk swizzle
  __shared__ bf16 Plds_all[8][16 * PSTR];
  bf16* Plds = &Plds_all[wv][0];

  const bf16* Qh  = Q  + (size_t)bh * SEQL * DK;
  const bf16* Kh  = K  + (size_t)bh * SEQL * DK;
  const bf16* Vth = Vt + (size_t)bh * DK * SEQL;
  const float* pb = padf + b * SEQL;

  // staging lane constants: waves 0-3 stage K (8 rows each), waves 4-7 stage V (16 d each)
  const bool stK = (wv < 4);
  const int kr = lane >> 3;                    // K: row within wave's 8-row slice
  const int kj = (lane & 7) ^ kr;              // K: global 16B chunk (XOR-3)
  const int vr = lane >> 2;                    // V: d within wave's 16-row slice
  const int vj = (lane & 3) ^ (vr & 3);        // V: global 16B chunk (XOR-2)
  const size_t sgoff = stK ? (size_t)(wv * 8 + kr) * DK + kj * 8
                           : (size_t)((wv - 4) * 16 + vr) * SEQL + vj * 8;
  const bf16* sgbase = stK ? Kh : Vth;
  bf16* sl0 = stK ? &KsS[0][(wv * 64 + lane) * 8] : &VsS[0][((wv - 4) * 64 + lane) * 8];
  bf16* sl1 = stK ? &KsS[1][(wv * 64 + lane) * 8] : &VsS[1][((wv - 4) * 64 + lane) * 8];
  const size_t sstep = stK ? (size_t)32 * DK : 32;  // advance per key-tile

  const float sc = 0.1803368801111204f;  // log2(e) / sqrt(64)

  for (int pass = 0; pass < 2; ++pass) {
    const int qt  = pass ? 15 - t : t;     // 128-row q-tile index
    const int R   = qt * 128 + wv * 16;    // wave's first q row
    const int nkt = (qt + 1) * 4;

    // Q fragments (B-operand): lane c = query, k = kh*32 + quad*8 + j
    bf16x8 Qf[2];
#pragma unroll
    for (int kh = 0; kh < 2; ++kh)
      Qf[kh] = *(const bf16x8*)&Qh[(size_t)(R + c) * DK + kh * 32 + quad * 8];

    f32x4 Oc[4] = {};
    float l_s = 0.f;

    __syncthreads();  // previous pass done reading buffers
    async16(sgbase + sgoff, sl0);  // stage tile 0 into buf 0

    for (int kt = 0; kt < nkt; ++kt) {
      const int cur = kt & 1;
      const int kb = kt * 32;
      __syncthreads();  // drains asyncs: buf[cur] ready; buf[nxt] free

      if (kt + 1 < nkt)
        async16(sgbase + (size_t)(kt + 1) * sstep + sgoff, (cur ? sl0 : sl1));
      if (kb > R + 15) continue;  // fully masked for this wave

      float4 bc[2];
#pragma unroll
      for (int kf = 0; kf < 2; ++kf)
        bc[kf] = *(const float4*)&pb[kb + kf * 16 + quad * 4];

      // LDS -> fragments
      bf16x8 Kf[2][2], Vf[4];
#pragma unroll
      for (int kf = 0; kf < 2; ++kf) {
        const int rloc = kf * 16 + c;
#pragma unroll
        for (int kh = 0; kh < 2; ++kh) {
          const int j = kh * 4 + quad;
          Kf[kf][kh] = *(const bf16x8*)&KsS[cur][(rloc * 8 + (j ^ (rloc & 7))) * 8];
        }
      }
#pragma unroll
      for (int df = 0; df < 4; ++df) {
        const int dloc = df * 16 + c;
        Vf[df] = *(const bf16x8*)&VsS[cur][(dloc * 4 + (quad ^ (dloc & 3))) * 8];
      }

      // S^T = K.Q^T  (col=query, row=key)
      f32x4 st[2] = {};
#pragma unroll
      for (int kh = 0; kh < 2; ++kh)
#pragma unroll
        for (int kf = 0; kf < 2; ++kf)
          st[kf] = __builtin_amdgcn_mfma_f32_16x16x32_bf16(Kf[kf][kh], Qf[kh],
                                                           st[kf], 0, 0, 0);

      // softmax (no max-subtraction) + P store; masked keys -> exp2(-3e38)=0
      const bool diag = (kb + 31 > R);
      float p8[8];
#pragma unroll
      for (int kf = 0; kf < 2; ++kf) {
        const float* bv4 = (const float*)&bc[kf];
#pragma unroll
        for (int r = 0; r < 4; ++r) {
          float e = __builtin_amdgcn_exp2f(__builtin_fmaf(st[kf][r], sc, bv4[r]));
          if (diag && (kb + kf * 16 + quad * 4 + r > R + c)) e = 0.f;
          p8[kf * 4 + r] = e;
          l_s += e;
        }
      }
      bf16x4 pk0 = {(bf16)p8[0], (bf16)p8[1], (bf16)p8[2], (bf16)p8[3]};
      bf16x4 pk1 = {(bf16)p8[4], (bf16)p8[5], (bf16)p8[6], (bf16)p8[7]};
      *(bf16x4*)&Plds[c * PSTR + quad * 4] = pk0;
      *(bf16x4*)&Plds[c * PSTR + 16 + quad * 4] = pk1;

      // O += P @ V
      bf16x8 af = *(const bf16x8*)&Plds[c * PSTR + quad * 8];
#pragma unroll
      for (int df = 0; df < 4; ++df)
        Oc[df] = __builtin_amdgcn_mfma_f32_16x16x32_bf16(af, Vf[df], Oc[df], 0, 0, 0);
    }

    // epilogue: reduce l across quads, divide, store
    float l = l_s;
    l += __shfl_xor(l, 16);
    l += __shfl_xor(l, 32);
    float linv = (l > 0.f) ? 1.f / l : 0.f;
    float lr[4];
#pragma unroll
    for (int r = 0; r < 4; ++r) lr[r] = __shfl(linv, quad * 4 + r);
#pragma unroll
    for (int r = 0; r < 4; ++r) {
      size_t row = (size_t)(b * SEQL + R + quad * 4 + r) * DM + h * DK;
#pragma unroll
      for (int df = 0; df < 4; ++df)
        O[row + df * 16 + c] = (bf16)(Oc[df][r] * lr[r]);
    }
  }
}

// ---------------- launch ----------------
extern "C" void kernel_launch(void* const* d_in, const int* in_sizes, int n_in,
                              void* d_out, int out_size, void* d_ws, size_t ws_size,
                              hipStream_t stream) {
  const float* x   = (const float*)d_in[0];
  const int*   pad = (const int*)d_in[1];
  const float* Wq  = (const float*)d_in[2];
  const float* bq  = (const float*)d_in[3];
  const float* Wk  = (const float*)d_in[4];
  const float* bk  = (const float*)d_in[5];
  const float* Wv  = (const float*)d_in[6];
  const float* bv  = (const float*)d_in[7];
  const float* Wo  = (const float*)d_in[8];
  const float* bo  = (const float*)d_in[9];
  float* out = (float*)d_out;

  const size_t SZ_X = (size_t)NTOK * DM * 2;  // 16 MB
  const size_t SZ_W = (size_t)DM * DM * 2;    // 2 MB
  char* ws = (char*)d_ws;
  bf16* Xb  = (bf16*)ws;  ws += SZ_X;
  bf16* Wqb = (bf16*)ws;  ws += SZ_W;
  bf16* Wkb = (bf16*)ws;  ws += SZ_W;
  bf16* Wvb = (bf16*)ws;  ws += SZ_W;
  bf16* Wob = (bf16*)ws;  ws += SZ_W;
  bf16* Qb  = (bf16*)ws;  ws += SZ_X;
  bf16* Kb  = (bf16*)ws;  ws += SZ_X;
  bf16* Vtb = (bf16*)ws;  ws += SZ_X;   // [B,H,dk,S]
  bf16* Ob  = (bf16*)ws;  ws += SZ_X;
  float* padfb = (float*)ws; ws += (size_t)NTOK * 4;

  cvt_all<<<6148, 256, 0, stream>>>(x, Wq, Wk, Wv, Wo, pad,
                                    Xb, Wqb, Wkb, Wvb, Wob, padfb);
  qkv_gemm<<<dim3(8, 64, 3), 256, 0, stream>>>(Xb, Wqb, Wkb, Wvb, bq, bk, bv, Qb, Kb, Vtb);
  attn_kernel<<<512, 512, 0, stream>>>(Qb, Kb, Vtb, padfb, Ob);
  out_gemm<<<dim3(8, 64), 256, 0, stream>>>(Ob, Wob, bo, out);
}